// Round 8
// baseline (109.365 us; speedup 1.0000x reference)
//
#include <hip/hip_runtime.h>

#define N_CELLS 100000
#define IN_CH 64
#define N_EDGES 1280000
#define NPASS 4      // source-range passes; slice = 12.8MB/4 = 3.2MB < 4MB XCD-L2
#define MAXCH 4      // up to 64 edges (4 chunks of 16) held in registers per group

// ---- bf16 helpers (bit-level, RNE) ----
__device__ __forceinline__ unsigned short f32_to_bf16(float f) {
    unsigned u = __float_as_uint(f);
    u += 0x7FFFu + ((u >> 16) & 1u);
    return (unsigned short)(u >> 16);
}
__device__ __forceinline__ float bf16_to_f32(unsigned short h) {
    return __uint_as_float((unsigned)h << 16);
}

#define SCORE_BLOCKS ((N_CELLS * 16 + 255) / 256)
#define ROWSTART_BLOCKS ((N_EDGES + 255) / 256)

// Fused prep: scores + bf16 x copy ([N][64] row layout, 128B rows) + CSR offsets.
__global__ void __launch_bounds__(256) prep_kernel(
    const float* __restrict__ x, const float* __restrict__ w,
    const int* __restrict__ tgt,
    float* __restrict__ s_src, float* __restrict__ s_tgt,
    unsigned short* __restrict__ xb, int* __restrict__ row_start,
    int n_cells, int n_edges) {
    if (blockIdx.x < SCORE_BLOCKS) {
        int gid  = blockIdx.x * 256 + threadIdx.x;
        int wave = gid >> 6;
        int lane = threadIdx.x & 63;
        int grp  = lane >> 4;
        int sub  = lane & 15;
        int cell = wave * 4 + grp;

        float4 xv = make_float4(0.f, 0.f, 0.f, 0.f);
        if (cell < n_cells)
            xv = *(const float4*)&x[(((unsigned)cell << 6) | ((unsigned)sub << 2))];
        if (cell < n_cells) {
            ushort4 hb;
            hb.x = f32_to_bf16(xv.x); hb.y = f32_to_bf16(xv.y);
            hb.z = f32_to_bf16(xv.z); hb.w = f32_to_bf16(xv.w);
            *(ushort4*)&xb[(((unsigned)cell << 6) | ((unsigned)sub << 2))] = hb;
        }
        const float4* w4 = (const float4*)w;
        float4 wa = w4[sub];
        float4 wb = w4[16 + sub];
        float a = xv.x * wa.x + xv.y * wa.y + xv.z * wa.z + xv.w * wa.w;
        float b = xv.x * wb.x + xv.y * wb.y + xv.z * wb.z + xv.w * wb.w;
#pragma unroll
        for (int off = 8; off; off >>= 1) {
            a += __shfl_xor(a, off, 64);
            b += __shfl_xor(b, off, 64);
        }
        if (sub == 0 && cell < n_cells) {
            s_src[cell] = a;
            s_tgt[cell] = b;
        }
    } else {
        int e = (blockIdx.x - SCORE_BLOCKS) * 256 + threadIdx.x;
        if (e >= n_edges) return;
        int lane = threadIdx.x & 63;
        int t = tgt[e];
        int prev = __shfl_up(t, 1, 64);
        if (lane == 0) prev = (e == 0) ? -1 : tgt[e - 1];
        for (int c = prev + 1; c <= t; ++c) row_start[c] = e;
        if (e == n_edges - 1) {
            for (int c = t + 1; c <= n_cells; ++c) row_start[c] = n_edges;
        }
    }
}

// Phased gather: one 16-lane group per cell. Edges (j,v) are loaded into
// registers once; then NPASS source-range passes gather only rows in the
// current 3.2MB slice. __syncthreads() between passes drains vmcnt and keeps
// co-resident blocks sweeping the same slice -> slice stays L2-resident.
__global__ void __launch_bounds__(256) agg_kernel_phase(
    const unsigned short* __restrict__ xb, const int* __restrict__ src,
    const float* __restrict__ nbhd,
    const float* __restrict__ s_src, const float* __restrict__ s_tgt,
    const int* __restrict__ row_start,
    float* __restrict__ out, int n_cells) {
    int gid  = blockIdx.x * blockDim.x + threadIdx.x;
    int lane = threadIdx.x & 63;
    int grp  = lane >> 4;
    int sub  = lane & 15;
    int cell = (gid >> 6) * 4 + grp;
    unsigned suboff = (unsigned)sub << 2;
    int gbase = grp << 4;

    bool valid = (cell < n_cells);
    int lo = 0, hi = 0;
    float sti = 0.f;
    if (valid) {
        lo  = row_start[cell];
        hi  = row_start[cell + 1];
        sti = s_tgt[cell];
    }
    int cnt  = hi - lo;
    int cntP = cnt > (MAXCH * 16) ? (MAXCH * 16) : cnt;   // phased portion

    // Load phase: up to 64 edges' (j, v) into registers, one per lane per chunk.
    int   jr[MAXCH];
    float vr[MAXCH];
#pragma unroll
    for (int c = 0; c < MAXCH; ++c) {
        int t16 = (c << 4) + sub;
        int j = -1; float v = 0.f;
        if (t16 < cntP) {
            int idx = lo + t16;
            j = src[idx];
            float a = s_src[j] + sti;
            v = nbhd[idx] * (a > 0.f ? a : expm1f(a));
        }
        jr[c] = j; vr[c] = v;
    }

    float4 acc = make_float4(0.f, 0.f, 0.f, 0.f);
    const int slice = (n_cells + NPASS - 1) / NPASS;
    for (int p = 0; p < NPASS; ++p) {
        int b0 = p * slice, b1 = b0 + slice;
#pragma unroll
        for (int c = 0; c < MAXCH; ++c) {
            int cc = cntP - (c << 4);
            if (cc > 16) cc = 16;
            int t = 0;
            for (; t + 4 <= cc; t += 4) {
                int   j0 = __shfl(jr[c], gbase + t,     64);
                int   j1 = __shfl(jr[c], gbase + t + 1, 64);
                int   j2 = __shfl(jr[c], gbase + t + 2, 64);
                int   j3 = __shfl(jr[c], gbase + t + 3, 64);
                float v0 = __shfl(vr[c], gbase + t,     64);
                float v1 = __shfl(vr[c], gbase + t + 1, 64);
                float v2 = __shfl(vr[c], gbase + t + 2, 64);
                float v3 = __shfl(vr[c], gbase + t + 3, 64);
                if (j0 >= b0 && j0 < b1) {
                    ushort4 h = *(const ushort4*)&xb[(((unsigned)j0 << 6) | suboff)];
                    acc.x = fmaf(v0, bf16_to_f32(h.x), acc.x);
                    acc.y = fmaf(v0, bf16_to_f32(h.y), acc.y);
                    acc.z = fmaf(v0, bf16_to_f32(h.z), acc.z);
                    acc.w = fmaf(v0, bf16_to_f32(h.w), acc.w);
                }
                if (j1 >= b0 && j1 < b1) {
                    ushort4 h = *(const ushort4*)&xb[(((unsigned)j1 << 6) | suboff)];
                    acc.x = fmaf(v1, bf16_to_f32(h.x), acc.x);
                    acc.y = fmaf(v1, bf16_to_f32(h.y), acc.y);
                    acc.z = fmaf(v1, bf16_to_f32(h.z), acc.z);
                    acc.w = fmaf(v1, bf16_to_f32(h.w), acc.w);
                }
                if (j2 >= b0 && j2 < b1) {
                    ushort4 h = *(const ushort4*)&xb[(((unsigned)j2 << 6) | suboff)];
                    acc.x = fmaf(v2, bf16_to_f32(h.x), acc.x);
                    acc.y = fmaf(v2, bf16_to_f32(h.y), acc.y);
                    acc.z = fmaf(v2, bf16_to_f32(h.z), acc.z);
                    acc.w = fmaf(v2, bf16_to_f32(h.w), acc.w);
                }
                if (j3 >= b0 && j3 < b1) {
                    ushort4 h = *(const ushort4*)&xb[(((unsigned)j3 << 6) | suboff)];
                    acc.x = fmaf(v3, bf16_to_f32(h.x), acc.x);
                    acc.y = fmaf(v3, bf16_to_f32(h.y), acc.y);
                    acc.z = fmaf(v3, bf16_to_f32(h.z), acc.z);
                    acc.w = fmaf(v3, bf16_to_f32(h.w), acc.w);
                }
            }
            for (; t < cc; ++t) {
                int   jt = __shfl(jr[c], gbase + t, 64);
                float vt = __shfl(vr[c], gbase + t, 64);
                if (jt >= b0 && jt < b1) {
                    ushort4 h = *(const ushort4*)&xb[(((unsigned)jt << 6) | suboff)];
                    acc.x = fmaf(vt, bf16_to_f32(h.x), acc.x);
                    acc.y = fmaf(vt, bf16_to_f32(h.y), acc.y);
                    acc.z = fmaf(vt, bf16_to_f32(h.z), acc.z);
                    acc.w = fmaf(vt, bf16_to_f32(h.w), acc.w);
                }
            }
        }
        // Drain outstanding gathers + re-sync the block before the next slice.
        if (p < NPASS - 1) __syncthreads();
    }

    // Fallback for rare cells with >64 edges (unphased, same as R5 loop).
    for (int base = lo + MAXCH * 16; base < hi; base += 16) {
        int cc = hi - base;
        if (cc > 16) cc = 16;
        int   j = 0;
        float v = 0.f;
        if (sub < cc) {
            j = src[base + sub];
            float a = s_src[j] + sti;
            v = nbhd[base + sub] * (a > 0.f ? a : expm1f(a));
        }
        for (int t = 0; t < cc; ++t) {
            int   jt = __shfl(j, gbase + t, 64);
            float vt = __shfl(v, gbase + t, 64);
            ushort4 h = *(const ushort4*)&xb[(((unsigned)jt << 6) | suboff)];
            acc.x = fmaf(vt, bf16_to_f32(h.x), acc.x);
            acc.y = fmaf(vt, bf16_to_f32(h.y), acc.y);
            acc.z = fmaf(vt, bf16_to_f32(h.z), acc.z);
            acc.w = fmaf(vt, bf16_to_f32(h.w), acc.w);
        }
    }

    if (valid)
        *(float4*)&out[(((unsigned)cell << 6) | suboff)] = acc;
}

// Fallback f32-gather version (used only if workspace is too small for xb).
__global__ void __launch_bounds__(256) agg_kernel_f32(
    const float* __restrict__ x, const int* __restrict__ src,
    const float* __restrict__ nbhd,
    const float* __restrict__ s_src, const float* __restrict__ s_tgt,
    const int* __restrict__ row_start,
    float* __restrict__ out, int n_cells) {
    int gid  = blockIdx.x * blockDim.x + threadIdx.x;
    int lane = threadIdx.x & 63;
    int grp  = lane >> 4;
    int sub  = lane & 15;
    int cell = (gid >> 6) * 4 + grp;
    unsigned suboff = (unsigned)sub << 2;
    int gbase = grp << 4;

    int lo = 0, hi = 0;
    float sti = 0.f;
    if (cell < n_cells) {
        lo  = row_start[cell];
        hi  = row_start[cell + 1];
        sti = s_tgt[cell];
    }
    float4 acc = make_float4(0.f, 0.f, 0.f, 0.f);
    for (int base = lo; base < hi; base += 16) {
        int cc = hi - base;
        if (cc > 16) cc = 16;
        int   j = 0;
        float v = 0.f;
        if (sub < cc) {
            j = src[base + sub];
            float a = s_src[j] + sti;
            v = nbhd[base + sub] * (a > 0.f ? a : expm1f(a));
        }
        for (int t = 0; t < cc; ++t) {
            int   jt = __shfl(j, gbase + t, 64);
            float vt = __shfl(v, gbase + t, 64);
            float4 xt = *(const float4*)&x[(((unsigned)jt << 6) | suboff)];
            acc.x = fmaf(vt, xt.x, acc.x); acc.y = fmaf(vt, xt.y, acc.y);
            acc.z = fmaf(vt, xt.z, acc.z); acc.w = fmaf(vt, xt.w, acc.w);
        }
    }
    if (cell < n_cells)
        *(float4*)&out[(((unsigned)cell << 6) | suboff)] = acc;
}

extern "C" void kernel_launch(void* const* d_in, const int* in_sizes, int n_in,
                              void* d_out, int out_size, void* d_ws, size_t ws_size,
                              hipStream_t stream) {
    const float* x    = (const float*)d_in[0];   // [N_CELLS, 64]
    const float* w    = (const float*)d_in[1];   // [128]
    const float* nbhd = (const float*)d_in[2];   // [N_EDGES]
    const int*   tgt  = (const int*)d_in[3];     // [N_EDGES] sorted
    const int*   src  = (const int*)d_in[4];     // [N_EDGES]
    float*       out  = (float*)d_out;           // [N_CELLS, 64]

    float* s_src     = (float*)d_ws;                       // N_CELLS f32
    float* s_tgt     = s_src + N_CELLS;                    // N_CELLS f32
    int*   row_start = (int*)(s_tgt + N_CELLS);            // N_CELLS+1 i32
    unsigned short* xb = (unsigned short*)(row_start + N_CELLS + 1);  // N_CELLS*64 bf16
    size_t need_bf16 = (size_t)(2 * N_CELLS + N_CELLS + 1) * 4 + (size_t)N_CELLS * IN_CH * 2;
    bool use_bf16 = ws_size >= need_bf16;

    if (use_bf16) {
        int blocks = SCORE_BLOCKS + ROWSTART_BLOCKS;
        prep_kernel<<<blocks, 256, 0, stream>>>(x, w, tgt, s_src, s_tgt, xb,
                                                row_start, N_CELLS, N_EDGES);
        int threads = 256;
        int ablocks = (N_CELLS * 16 + threads - 1) / threads;
        agg_kernel_phase<<<ablocks, threads, 0, stream>>>(xb, src, nbhd, s_src, s_tgt,
                                                          row_start, out, N_CELLS);
    } else {
        int blocks = SCORE_BLOCKS + ROWSTART_BLOCKS;
        prep_kernel<<<blocks, 256, 0, stream>>>(x, w, tgt, s_src, s_tgt,
                                                (unsigned short*)nullptr,
                                                row_start, N_CELLS, N_EDGES);
        int threads = 256;
        int ablocks = (N_CELLS * 16 + threads - 1) / threads;
        agg_kernel_f32<<<ablocks, threads, 0, stream>>>(x, src, nbhd, s_src, s_tgt,
                                                        row_start, out, N_CELLS);
    }
}

// Round 9
// 67.893 us; speedup vs baseline: 1.6109x; 1.6109x over previous
//
#include <hip/hip_runtime.h>

#define N_CELLS 100000
#define IN_CH 64
#define N_EDGES 1280000
#define NSEG 4     // source-range segments; slice = 12.8MB/4 = 3.2MB < 4MB XCD-L2
#define MAXW 4     // windows of 16 edges cached/compacted in registers (64 edges)

// ---- bf16 helpers (bit-level, RNE) ----
__device__ __forceinline__ unsigned short f32_to_bf16(float f) {
    unsigned u = __float_as_uint(f);
    u += 0x7FFFu + ((u >> 16) & 1u);
    return (unsigned short)(u >> 16);
}
__device__ __forceinline__ float bf16_to_f32(unsigned short h) {
    return __uint_as_float((unsigned)h << 16);
}

#define SCORE_BLOCKS ((N_CELLS * 16 + 255) / 256)
#define ROWSTART_BLOCKS ((N_EDGES + 255) / 256)

// Fused prep: scores + bf16 x copy ([N][64] rows = 128B lines) + CSR offsets.
__global__ void __launch_bounds__(256) prep_kernel(
    const float* __restrict__ x, const float* __restrict__ w,
    const int* __restrict__ tgt,
    float* __restrict__ s_src, float* __restrict__ s_tgt,
    unsigned short* __restrict__ xb, int* __restrict__ row_start,
    int n_cells, int n_edges) {
    if (blockIdx.x < SCORE_BLOCKS) {
        int gid  = blockIdx.x * 256 + threadIdx.x;
        int wave = gid >> 6;
        int lane = threadIdx.x & 63;
        int grp  = lane >> 4;
        int sub  = lane & 15;
        int cell = wave * 4 + grp;

        float4 xv = make_float4(0.f, 0.f, 0.f, 0.f);
        if (cell < n_cells)
            xv = *(const float4*)&x[(((unsigned)cell << 6) | ((unsigned)sub << 2))];
        if (xb && cell < n_cells) {
            ushort4 hb;
            hb.x = f32_to_bf16(xv.x); hb.y = f32_to_bf16(xv.y);
            hb.z = f32_to_bf16(xv.z); hb.w = f32_to_bf16(xv.w);
            *(ushort4*)&xb[(((unsigned)cell << 6) | ((unsigned)sub << 2))] = hb;
        }
        const float4* w4 = (const float4*)w;
        float4 wa = w4[sub];
        float4 wb = w4[16 + sub];
        float a = xv.x * wa.x + xv.y * wa.y + xv.z * wa.z + xv.w * wa.w;
        float b = xv.x * wb.x + xv.y * wb.y + xv.z * wb.z + xv.w * wb.w;
#pragma unroll
        for (int off = 8; off; off >>= 1) {
            a += __shfl_xor(a, off, 64);
            b += __shfl_xor(b, off, 64);
        }
        if (sub == 0 && cell < n_cells) {
            s_src[cell] = a;
            s_tgt[cell] = b;
        }
    } else {
        int e = (blockIdx.x - SCORE_BLOCKS) * 256 + threadIdx.x;
        if (e >= n_edges) return;
        int lane = threadIdx.x & 63;
        int t = tgt[e];
        int prev = __shfl_up(t, 1, 64);
        if (lane == 0) prev = (e == 0) ? -1 : tgt[e - 1];
        for (int c = prev + 1; c <= t; ++c) row_start[c] = e;
        if (e == n_edges - 1) {
            for (int c = t + 1; c <= n_cells; ++c) row_start[c] = n_edges;
        }
    }
}

// Segmented gather: one 16-lane group per cell (grid exactly covers n_cells; no
// early returns -> barriers are uniform). Each 16-edge window is compacted
// in-register by source-range bucket (ballot+rank+ds_permute), then the 4
// segments are walked UNCONDITIONALLY (total slots = cnt) with 4-deep bursts;
// __syncthreads() between segments keeps co-resident blocks on the same 3.2MB
// slice so it stays L2-resident.
__global__ void __launch_bounds__(256) agg_kernel_seg(
    const unsigned short* __restrict__ xb, const int* __restrict__ src,
    const float* __restrict__ nbhd,
    const float* __restrict__ s_src, const float* __restrict__ s_tgt,
    const int* __restrict__ row_start,
    float* __restrict__ out, int n_cells) {
    int gid  = blockIdx.x * blockDim.x + threadIdx.x;
    int lane = threadIdx.x & 63;
    int grp  = lane >> 4;
    int sub  = lane & 15;
    int cell = (gid >> 6) * 4 + grp;          // always < n_cells (grid exact)
    unsigned suboff = (unsigned)sub << 2;
    int gbase = grp << 4;

    int lo  = row_start[cell];
    int hi  = row_start[cell + 1];
    float sti = s_tgt[cell];
    int cnt  = hi - lo;
    int cntP = cnt > (MAXW * 16) ? (MAXW * 16) : cnt;

    const int q = (N_CELLS + NSEG - 1) / NSEG;   // 25000

    int      jr[MAXW];
    float    vr[MAXW];
    unsigned bb[MAXW];   // packed cumulative boundaries: s1|s2<<5|s3<<10|s4<<15

#pragma unroll
    for (int c = 0; c < MAXW; ++c) {
        int wcnt = cntP - (c << 4);
        wcnt = wcnt < 0 ? 0 : (wcnt > 16 ? 16 : wcnt);
        bool act = sub < wcnt;
        int j = 0; float v = 0.f;
        if (act) {
            int idx = lo + (c << 4) + sub;
            j = src[idx];
            float a = s_src[j] + sti;
            v = nbhd[idx] * (a > 0.f ? a : expm1f(a));
        }
        int b = act ? ((j >= 3 * q) ? 3 : (j >= 2 * q) ? 2 : (j >= q) ? 1 : 0) : 4;
        unsigned long long m0 = __ballot(b == 0);
        unsigned long long m1 = __ballot(b == 1);
        unsigned long long m2 = __ballot(b == 2);
        unsigned long long m3 = __ballot(b == 3);
        unsigned f0 = (unsigned)(m0 >> gbase) & 0xFFFFu;
        unsigned f1 = (unsigned)(m1 >> gbase) & 0xFFFFu;
        unsigned f2 = (unsigned)(m2 >> gbase) & 0xFFFFu;
        unsigned f3 = (unsigned)(m3 >> gbase) & 0xFFFFu;
        unsigned below = (1u << sub) - 1u;
        int c0 = __popc(f0), c1 = __popc(f1), c2 = __popc(f2), c3 = __popc(f3);
        int slot;
        if (b == 0)      slot = __popc(f0 & below);
        else if (b == 1) slot = c0 + __popc(f1 & below);
        else if (b == 2) slot = c0 + c1 + __popc(f2 & below);
        else if (b == 3) slot = c0 + c1 + c2 + __popc(f3 & below);
        else {
            unsigned f4 = ~(f0 | f1 | f2 | f3) & 0xFFFFu;
            slot = c0 + c1 + c2 + c3 + __popc(f4 & below);
        }
        int dst = (gbase + slot) << 2;   // byte address of destination lane
        jr[c] = __builtin_amdgcn_ds_permute(dst, j);
        vr[c] = __int_as_float(__builtin_amdgcn_ds_permute(dst, __float_as_int(v)));
        bb[c] = (unsigned)c0 | ((unsigned)(c0 + c1) << 5)
              | ((unsigned)(c0 + c1 + c2) << 10)
              | ((unsigned)(c0 + c1 + c2 + c3) << 15);
    }

    float4 acc = make_float4(0.f, 0.f, 0.f, 0.f);
#pragma unroll
    for (int s = 0; s < NSEG; ++s) {
#pragma unroll
        for (int c = 0; c < MAXW; ++c) {
            int t0 = (s == 0) ? 0 : (int)((bb[c] >> (5 * (s - 1))) & 31u);
            int t1 = (int)((bb[c] >> (5 * s)) & 31u);
            int t = t0;
            for (; t + 4 <= t1; t += 4) {
                int   j0 = __shfl(jr[c], gbase + t,     64);
                int   j1 = __shfl(jr[c], gbase + t + 1, 64);
                int   j2 = __shfl(jr[c], gbase + t + 2, 64);
                int   j3 = __shfl(jr[c], gbase + t + 3, 64);
                float v0 = __shfl(vr[c], gbase + t,     64);
                float v1 = __shfl(vr[c], gbase + t + 1, 64);
                float v2 = __shfl(vr[c], gbase + t + 2, 64);
                float v3 = __shfl(vr[c], gbase + t + 3, 64);
                ushort4 h0 = *(const ushort4*)&xb[(((unsigned)j0 << 6) | suboff)];
                ushort4 h1 = *(const ushort4*)&xb[(((unsigned)j1 << 6) | suboff)];
                ushort4 h2 = *(const ushort4*)&xb[(((unsigned)j2 << 6) | suboff)];
                ushort4 h3 = *(const ushort4*)&xb[(((unsigned)j3 << 6) | suboff)];
                acc.x = fmaf(v0, bf16_to_f32(h0.x), acc.x);
                acc.y = fmaf(v0, bf16_to_f32(h0.y), acc.y);
                acc.z = fmaf(v0, bf16_to_f32(h0.z), acc.z);
                acc.w = fmaf(v0, bf16_to_f32(h0.w), acc.w);
                acc.x = fmaf(v1, bf16_to_f32(h1.x), acc.x);
                acc.y = fmaf(v1, bf16_to_f32(h1.y), acc.y);
                acc.z = fmaf(v1, bf16_to_f32(h1.z), acc.z);
                acc.w = fmaf(v1, bf16_to_f32(h1.w), acc.w);
                acc.x = fmaf(v2, bf16_to_f32(h2.x), acc.x);
                acc.y = fmaf(v2, bf16_to_f32(h2.y), acc.y);
                acc.z = fmaf(v2, bf16_to_f32(h2.z), acc.z);
                acc.w = fmaf(v2, bf16_to_f32(h2.w), acc.w);
                acc.x = fmaf(v3, bf16_to_f32(h3.x), acc.x);
                acc.y = fmaf(v3, bf16_to_f32(h3.y), acc.y);
                acc.z = fmaf(v3, bf16_to_f32(h3.z), acc.z);
                acc.w = fmaf(v3, bf16_to_f32(h3.w), acc.w);
            }
            for (; t < t1; ++t) {
                int   jt = __shfl(jr[c], gbase + t, 64);
                float vt = __shfl(vr[c], gbase + t, 64);
                ushort4 h = *(const ushort4*)&xb[(((unsigned)jt << 6) | suboff)];
                acc.x = fmaf(vt, bf16_to_f32(h.x), acc.x);
                acc.y = fmaf(vt, bf16_to_f32(h.y), acc.y);
                acc.z = fmaf(vt, bf16_to_f32(h.z), acc.z);
                acc.w = fmaf(vt, bf16_to_f32(h.w), acc.w);
            }
        }
        if (s < NSEG - 1) __syncthreads();   // uniform: no thread exits early
    }

    // Unphased tail for rare cells with >64 edges (no barriers).
    for (int base = lo + MAXW * 16; base < hi; base += 16) {
        int cc = hi - base;
        if (cc > 16) cc = 16;
        int   j = 0;
        float v = 0.f;
        if (sub < cc) {
            j = src[base + sub];
            float a = s_src[j] + sti;
            v = nbhd[base + sub] * (a > 0.f ? a : expm1f(a));
        }
        for (int t = 0; t < cc; ++t) {
            int   jt = __shfl(j, gbase + t, 64);
            float vt = __shfl(v, gbase + t, 64);
            ushort4 h = *(const ushort4*)&xb[(((unsigned)jt << 6) | suboff)];
            acc.x = fmaf(vt, bf16_to_f32(h.x), acc.x);
            acc.y = fmaf(vt, bf16_to_f32(h.y), acc.y);
            acc.z = fmaf(vt, bf16_to_f32(h.z), acc.z);
            acc.w = fmaf(vt, bf16_to_f32(h.w), acc.w);
        }
    }

    *(float4*)&out[(((unsigned)cell << 6) | suboff)] = acc;
}

// Fallback f32-gather version (used only if workspace is too small for xb).
__global__ void __launch_bounds__(256) agg_kernel_f32(
    const float* __restrict__ x, const int* __restrict__ src,
    const float* __restrict__ nbhd,
    const float* __restrict__ s_src, const float* __restrict__ s_tgt,
    const int* __restrict__ row_start,
    float* __restrict__ out, int n_cells) {
    int gid  = blockIdx.x * blockDim.x + threadIdx.x;
    int lane = threadIdx.x & 63;
    int grp  = lane >> 4;
    int sub  = lane & 15;
    int cell = (gid >> 6) * 4 + grp;
    unsigned suboff = (unsigned)sub << 2;
    int gbase = grp << 4;

    int lo = 0, hi = 0;
    float sti = 0.f;
    if (cell < n_cells) {
        lo  = row_start[cell];
        hi  = row_start[cell + 1];
        sti = s_tgt[cell];
    }
    float4 acc = make_float4(0.f, 0.f, 0.f, 0.f);
    for (int base = lo; base < hi; base += 16) {
        int cc = hi - base;
        if (cc > 16) cc = 16;
        int   j = 0;
        float v = 0.f;
        if (sub < cc) {
            j = src[base + sub];
            float a = s_src[j] + sti;
            v = nbhd[base + sub] * (a > 0.f ? a : expm1f(a));
        }
        for (int t = 0; t < cc; ++t) {
            int   jt = __shfl(j, gbase + t, 64);
            float vt = __shfl(v, gbase + t, 64);
            float4 xt = *(const float4*)&x[(((unsigned)jt << 6) | suboff)];
            acc.x = fmaf(vt, xt.x, acc.x); acc.y = fmaf(vt, xt.y, acc.y);
            acc.z = fmaf(vt, xt.z, acc.z); acc.w = fmaf(vt, xt.w, acc.w);
        }
    }
    if (cell < n_cells)
        *(float4*)&out[(((unsigned)cell << 6) | suboff)] = acc;
}

extern "C" void kernel_launch(void* const* d_in, const int* in_sizes, int n_in,
                              void* d_out, int out_size, void* d_ws, size_t ws_size,
                              hipStream_t stream) {
    const float* x    = (const float*)d_in[0];   // [N_CELLS, 64]
    const float* w    = (const float*)d_in[1];   // [128]
    const float* nbhd = (const float*)d_in[2];   // [N_EDGES]
    const int*   tgt  = (const int*)d_in[3];     // [N_EDGES] sorted
    const int*   src  = (const int*)d_in[4];     // [N_EDGES]
    float*       out  = (float*)d_out;           // [N_CELLS, 64]

    float* s_src     = (float*)d_ws;                       // N_CELLS f32
    float* s_tgt     = s_src + N_CELLS;                    // N_CELLS f32
    int*   row_start = (int*)(s_tgt + N_CELLS);            // N_CELLS+1 i32
    unsigned short* xb = (unsigned short*)(row_start + N_CELLS + 1);  // N_CELLS*64 bf16
    size_t need_bf16 = (size_t)(2 * N_CELLS + N_CELLS + 1) * 4 + (size_t)N_CELLS * IN_CH * 2;
    bool use_bf16 = ws_size >= need_bf16;

    if (use_bf16) {
        int blocks = SCORE_BLOCKS + ROWSTART_BLOCKS;
        prep_kernel<<<blocks, 256, 0, stream>>>(x, w, tgt, s_src, s_tgt, xb,
                                                row_start, N_CELLS, N_EDGES);
        int ablocks = (N_CELLS * 16) / 256;                // exactly 6250
        agg_kernel_seg<<<ablocks, 256, 0, stream>>>(xb, src, nbhd, s_src, s_tgt,
                                                    row_start, out, N_CELLS);
    } else {
        int blocks = SCORE_BLOCKS + ROWSTART_BLOCKS;
        prep_kernel<<<blocks, 256, 0, stream>>>(x, w, tgt, s_src, s_tgt,
                                                (unsigned short*)nullptr,
                                                row_start, N_CELLS, N_EDGES);
        int threads = 256;
        int ablocks = (N_CELLS * 16 + threads - 1) / threads;
        agg_kernel_f32<<<ablocks, threads, 0, stream>>>(x, src, nbhd, s_src, s_tgt,
                                                        row_start, out, N_CELLS);
    }
}

// Round 10
// 64.709 us; speedup vs baseline: 1.6901x; 1.0492x over previous
//
#include <hip/hip_runtime.h>

#define N_CELLS 100000
#define IN_CH 64
#define N_EDGES 1280000
#define MAXW 4   // 4 windows of 16 edges cached in registers (covers deg <= 64)

// ---- bf16 helpers (bit-level, RNE) ----
__device__ __forceinline__ unsigned short f32_to_bf16(float f) {
    unsigned u = __float_as_uint(f);
    u += 0x7FFFu + ((u >> 16) & 1u);
    return (unsigned short)(u >> 16);
}
__device__ __forceinline__ float bf16_to_f32(unsigned short h) {
    return __uint_as_float((unsigned)h << 16);
}

// Kernel A (cell-parallel): per-cell scores + bf16 x copy ([N][64] rows = 128B lines).
__global__ void __launch_bounds__(256) score_kernel(
    const float* __restrict__ x, const float* __restrict__ w,
    float* __restrict__ s_src, float* __restrict__ s_tgt,
    unsigned short* __restrict__ xb, int n_cells) {
    int gid  = blockIdx.x * 256 + threadIdx.x;
    int wave = gid >> 6;
    int lane = threadIdx.x & 63;
    int grp  = lane >> 4;
    int sub  = lane & 15;
    int cell = wave * 4 + grp;

    float4 xv = make_float4(0.f, 0.f, 0.f, 0.f);
    if (cell < n_cells)
        xv = *(const float4*)&x[(((unsigned)cell << 6) | ((unsigned)sub << 2))];
    if (xb && cell < n_cells) {
        ushort4 hb;
        hb.x = f32_to_bf16(xv.x); hb.y = f32_to_bf16(xv.y);
        hb.z = f32_to_bf16(xv.z); hb.w = f32_to_bf16(xv.w);
        *(ushort4*)&xb[(((unsigned)cell << 6) | ((unsigned)sub << 2))] = hb;
    }
    const float4* w4 = (const float4*)w;
    float4 wa = w4[sub];
    float4 wb = w4[16 + sub];
    float a = xv.x * wa.x + xv.y * wa.y + xv.z * wa.z + xv.w * wa.w;
    float b = xv.x * wb.x + xv.y * wb.y + xv.z * wb.z + xv.w * wb.w;
#pragma unroll
    for (int off = 8; off; off >>= 1) {
        a += __shfl_xor(a, off, 64);
        b += __shfl_xor(b, off, 64);
    }
    if (sub == 0 && cell < n_cells) {
        s_src[cell] = a;
        s_tgt[cell] = b;
    }
}

// Kernel B (edge-parallel): CSR row offsets + per-edge attention values.
// vals[e] = nbhd[e] * elu(s_src[src[e]] + s_tgt[tgt[e]]). Latency fully hidden
// by 1.28M threads; removes the random s_src gather + expm1 from the agg kernel.
__global__ void __launch_bounds__(256) edge_kernel(
    const int* __restrict__ tgt, const int* __restrict__ src,
    const float* __restrict__ nbhd,
    const float* __restrict__ s_src, const float* __restrict__ s_tgt,
    int* __restrict__ row_start, float* __restrict__ vals,
    int n_edges, int n_cells) {
    int e = blockIdx.x * 256 + threadIdx.x;
    if (e >= n_edges) return;
    int lane = threadIdx.x & 63;
    int t = tgt[e];
    float a = s_src[src[e]] + s_tgt[t];
    vals[e] = nbhd[e] * (a > 0.f ? a : expm1f(a));
    int prev = __shfl_up(t, 1, 64);
    if (lane == 0) prev = (e == 0) ? -1 : tgt[e - 1];
    for (int c = prev + 1; c <= t; ++c) row_start[c] = e;
    if (e == n_edges - 1) {
        for (int c = t + 1; c <= n_cells; ++c) row_start[c] = n_edges;
    }
}

// Kernel C: one 16-lane group per cell (grid exact). Two memory round trips:
// row_start -> all windows' (src, vals) issued together -> one unbroken
// 8/4/1-deep x-gather burst. No expm1, no s_src/s_tgt in this kernel.
__global__ void __launch_bounds__(256) agg_kernel(
    const unsigned short* __restrict__ xb, const int* __restrict__ src,
    const float* __restrict__ vals, const int* __restrict__ row_start,
    float* __restrict__ out, int n_cells) {
    int gid  = blockIdx.x * 256 + threadIdx.x;
    int lane = threadIdx.x & 63;
    int grp  = lane >> 4;
    int sub  = lane & 15;
    int cell = (gid >> 6) * 4 + grp;          // grid exact: always < n_cells
    unsigned suboff = (unsigned)sub << 2;
    int gbase = grp << 4;

    int lo  = row_start[cell];
    int hi  = row_start[cell + 1];
    int cnt = hi - lo;
    int cntP = cnt > (MAXW * 16) ? (MAXW * 16) : cnt;

    // Upfront register cache: all windows' (j, v) loads issue back-to-back.
    int   jr[MAXW];
    float vr[MAXW];
#pragma unroll
    for (int c = 0; c < MAXW; ++c) {
        int t16 = (c << 4) + sub;
        int j = 0; float v = 0.f;
        if (t16 < cntP) {
            int idx = lo + t16;
            j = src[idx];
            v = vals[idx];
        }
        jr[c] = j; vr[c] = v;
    }

    float4 acc = make_float4(0.f, 0.f, 0.f, 0.f);
#pragma unroll
    for (int c = 0; c < MAXW; ++c) {
        int wc = cntP - (c << 4);
        if (wc <= 0) break;
        if (wc > 16) wc = 16;
        int t = 0;
        for (; t + 8 <= wc; t += 8) {
#pragma unroll
            for (int u = 0; u < 8; u += 4) {
                int   j0 = __shfl(jr[c], gbase + t + u,     64);
                int   j1 = __shfl(jr[c], gbase + t + u + 1, 64);
                int   j2 = __shfl(jr[c], gbase + t + u + 2, 64);
                int   j3 = __shfl(jr[c], gbase + t + u + 3, 64);
                float v0 = __shfl(vr[c], gbase + t + u,     64);
                float v1 = __shfl(vr[c], gbase + t + u + 1, 64);
                float v2 = __shfl(vr[c], gbase + t + u + 2, 64);
                float v3 = __shfl(vr[c], gbase + t + u + 3, 64);
                ushort4 h0 = *(const ushort4*)&xb[(((unsigned)j0 << 6) | suboff)];
                ushort4 h1 = *(const ushort4*)&xb[(((unsigned)j1 << 6) | suboff)];
                ushort4 h2 = *(const ushort4*)&xb[(((unsigned)j2 << 6) | suboff)];
                ushort4 h3 = *(const ushort4*)&xb[(((unsigned)j3 << 6) | suboff)];
                acc.x = fmaf(v0, bf16_to_f32(h0.x), acc.x);
                acc.y = fmaf(v0, bf16_to_f32(h0.y), acc.y);
                acc.z = fmaf(v0, bf16_to_f32(h0.z), acc.z);
                acc.w = fmaf(v0, bf16_to_f32(h0.w), acc.w);
                acc.x = fmaf(v1, bf16_to_f32(h1.x), acc.x);
                acc.y = fmaf(v1, bf16_to_f32(h1.y), acc.y);
                acc.z = fmaf(v1, bf16_to_f32(h1.z), acc.z);
                acc.w = fmaf(v1, bf16_to_f32(h1.w), acc.w);
                acc.x = fmaf(v2, bf16_to_f32(h2.x), acc.x);
                acc.y = fmaf(v2, bf16_to_f32(h2.y), acc.y);
                acc.z = fmaf(v2, bf16_to_f32(h2.z), acc.z);
                acc.w = fmaf(v2, bf16_to_f32(h2.w), acc.w);
                acc.x = fmaf(v3, bf16_to_f32(h3.x), acc.x);
                acc.y = fmaf(v3, bf16_to_f32(h3.y), acc.y);
                acc.z = fmaf(v3, bf16_to_f32(h3.z), acc.z);
                acc.w = fmaf(v3, bf16_to_f32(h3.w), acc.w);
            }
        }
        for (; t + 4 <= wc; t += 4) {
            int   j0 = __shfl(jr[c], gbase + t,     64);
            int   j1 = __shfl(jr[c], gbase + t + 1, 64);
            int   j2 = __shfl(jr[c], gbase + t + 2, 64);
            int   j3 = __shfl(jr[c], gbase + t + 3, 64);
            float v0 = __shfl(vr[c], gbase + t,     64);
            float v1 = __shfl(vr[c], gbase + t + 1, 64);
            float v2 = __shfl(vr[c], gbase + t + 2, 64);
            float v3 = __shfl(vr[c], gbase + t + 3, 64);
            ushort4 h0 = *(const ushort4*)&xb[(((unsigned)j0 << 6) | suboff)];
            ushort4 h1 = *(const ushort4*)&xb[(((unsigned)j1 << 6) | suboff)];
            ushort4 h2 = *(const ushort4*)&xb[(((unsigned)j2 << 6) | suboff)];
            ushort4 h3 = *(const ushort4*)&xb[(((unsigned)j3 << 6) | suboff)];
            acc.x = fmaf(v0, bf16_to_f32(h0.x), acc.x);
            acc.y = fmaf(v0, bf16_to_f32(h0.y), acc.y);
            acc.z = fmaf(v0, bf16_to_f32(h0.z), acc.z);
            acc.w = fmaf(v0, bf16_to_f32(h0.w), acc.w);
            acc.x = fmaf(v1, bf16_to_f32(h1.x), acc.x);
            acc.y = fmaf(v1, bf16_to_f32(h1.y), acc.y);
            acc.z = fmaf(v1, bf16_to_f32(h1.z), acc.z);
            acc.w = fmaf(v1, bf16_to_f32(h1.w), acc.w);
            acc.x = fmaf(v2, bf16_to_f32(h2.x), acc.x);
            acc.y = fmaf(v2, bf16_to_f32(h2.y), acc.y);
            acc.z = fmaf(v2, bf16_to_f32(h2.z), acc.z);
            acc.w = fmaf(v2, bf16_to_f32(h2.w), acc.w);
            acc.x = fmaf(v3, bf16_to_f32(h3.x), acc.x);
            acc.y = fmaf(v3, bf16_to_f32(h3.y), acc.y);
            acc.z = fmaf(v3, bf16_to_f32(h3.z), acc.z);
            acc.w = fmaf(v3, bf16_to_f32(h3.w), acc.w);
        }
        for (; t < wc; ++t) {
            int   jt = __shfl(jr[c], gbase + t, 64);
            float vt = __shfl(vr[c], gbase + t, 64);
            ushort4 h = *(const ushort4*)&xb[(((unsigned)jt << 6) | suboff)];
            acc.x = fmaf(vt, bf16_to_f32(h.x), acc.x);
            acc.y = fmaf(vt, bf16_to_f32(h.y), acc.y);
            acc.z = fmaf(vt, bf16_to_f32(h.z), acc.z);
            acc.w = fmaf(vt, bf16_to_f32(h.w), acc.w);
        }
    }

    // Tail for deg > 64 (statistically absent here; kept for safety).
    for (int base = lo + MAXW * 16; base < hi; base += 16) {
        int cc = hi - base;
        if (cc > 16) cc = 16;
        int   j = 0;
        float v = 0.f;
        if (sub < cc) {
            j = src[base + sub];
            v = vals[base + sub];
        }
        for (int t = 0; t < cc; ++t) {
            int   jt = __shfl(j, gbase + t, 64);
            float vt = __shfl(v, gbase + t, 64);
            ushort4 h = *(const ushort4*)&xb[(((unsigned)jt << 6) | suboff)];
            acc.x = fmaf(vt, bf16_to_f32(h.x), acc.x);
            acc.y = fmaf(vt, bf16_to_f32(h.y), acc.y);
            acc.z = fmaf(vt, bf16_to_f32(h.z), acc.z);
            acc.w = fmaf(vt, bf16_to_f32(h.w), acc.w);
        }
    }

    *(float4*)&out[(((unsigned)cell << 6) | suboff)] = acc;
}

// Fallback f32-gather (only if workspace too small for xb+vals).
__global__ void __launch_bounds__(256) agg_kernel_f32(
    const float* __restrict__ x, const int* __restrict__ src,
    const float* __restrict__ nbhd,
    const float* __restrict__ s_src, const float* __restrict__ s_tgt,
    const int* __restrict__ row_start,
    float* __restrict__ out, int n_cells) {
    int gid  = blockIdx.x * 256 + threadIdx.x;
    int lane = threadIdx.x & 63;
    int grp  = lane >> 4;
    int sub  = lane & 15;
    int cell = (gid >> 6) * 4 + grp;
    unsigned suboff = (unsigned)sub << 2;
    int gbase = grp << 4;

    int lo = 0, hi = 0;
    float sti = 0.f;
    if (cell < n_cells) {
        lo  = row_start[cell];
        hi  = row_start[cell + 1];
        sti = s_tgt[cell];
    }
    float4 acc = make_float4(0.f, 0.f, 0.f, 0.f);
    for (int base = lo; base < hi; base += 16) {
        int cc = hi - base;
        if (cc > 16) cc = 16;
        int   j = 0;
        float v = 0.f;
        if (sub < cc) {
            j = src[base + sub];
            float a = s_src[j] + sti;
            v = nbhd[base + sub] * (a > 0.f ? a : expm1f(a));
        }
        for (int t = 0; t < cc; ++t) {
            int   jt = __shfl(j, gbase + t, 64);
            float vt = __shfl(v, gbase + t, 64);
            float4 xt = *(const float4*)&x[(((unsigned)jt << 6) | suboff)];
            acc.x = fmaf(vt, xt.x, acc.x); acc.y = fmaf(vt, xt.y, acc.y);
            acc.z = fmaf(vt, xt.z, acc.z); acc.w = fmaf(vt, xt.w, acc.w);
        }
    }
    if (cell < n_cells)
        *(float4*)&out[(((unsigned)cell << 6) | suboff)] = acc;
}

extern "C" void kernel_launch(void* const* d_in, const int* in_sizes, int n_in,
                              void* d_out, int out_size, void* d_ws, size_t ws_size,
                              hipStream_t stream) {
    const float* x    = (const float*)d_in[0];   // [N_CELLS, 64]
    const float* w    = (const float*)d_in[1];   // [128]
    const float* nbhd = (const float*)d_in[2];   // [N_EDGES]
    const int*   tgt  = (const int*)d_in[3];     // [N_EDGES] sorted
    const int*   src  = (const int*)d_in[4];     // [N_EDGES]
    float*       out  = (float*)d_out;           // [N_CELLS, 64]

    // workspace: s_src, s_tgt, row_start, vals, xb  (~19.3 MB)
    float* s_src     = (float*)d_ws;                              // N_CELLS
    float* s_tgt     = s_src + N_CELLS;                           // N_CELLS
    int*   row_start = (int*)(s_tgt + N_CELLS);                   // N_CELLS+1
    float* vals      = (float*)(row_start + N_CELLS + 1);         // N_EDGES
    unsigned short* xb = (unsigned short*)(vals + N_EDGES);       // N_CELLS*64
    size_t need_full = (size_t)(3 * N_CELLS + 1 + N_EDGES) * 4
                     + (size_t)N_CELLS * IN_CH * 2;
    bool full = ws_size >= need_full;

    int sblocks = (N_CELLS * 16 + 255) / 256;
    int eblocks = (N_EDGES + 255) / 256;

    if (full) {
        score_kernel<<<sblocks, 256, 0, stream>>>(x, w, s_src, s_tgt, xb, N_CELLS);
        edge_kernel<<<eblocks, 256, 0, stream>>>(tgt, src, nbhd, s_src, s_tgt,
                                                 row_start, vals, N_EDGES, N_CELLS);
        int ablocks = (N_CELLS * 16) / 256;   // exactly 6250
        agg_kernel<<<ablocks, 256, 0, stream>>>(xb, src, vals, row_start, out, N_CELLS);
    } else {
        score_kernel<<<sblocks, 256, 0, stream>>>(x, w, s_src, s_tgt,
                                                  (unsigned short*)nullptr, N_CELLS);
        edge_kernel<<<eblocks, 256, 0, stream>>>(tgt, src, nbhd, s_src, s_tgt,
                                                 row_start, vals, N_EDGES, N_CELLS);
        int ablocks = (N_CELLS * 16 + 255) / 256;
        agg_kernel_f32<<<ablocks, 256, 0, stream>>>(x, src, nbhd, s_src, s_tgt,
                                                    row_start, out, N_CELLS);
    }
}

// Round 11
// 59.723 us; speedup vs baseline: 1.8312x; 1.0835x over previous
//
#include <hip/hip_runtime.h>

#define N_CELLS 100000
#define IN_CH 64
#define N_EDGES 1280000
#define MAXW 4   // 4 windows of 16 edges cached in registers (covers deg <= 64)

// ---- bf16 helpers (bit-level, RNE) ----
__device__ __forceinline__ unsigned short f32_to_bf16(float f) {
    unsigned u = __float_as_uint(f);
    u += 0x7FFFu + ((u >> 16) & 1u);
    return (unsigned short)(u >> 16);
}
__device__ __forceinline__ float bf16_to_f32(unsigned short h) {
    return __uint_as_float((unsigned)h << 16);
}
// branchless ELU: exp path is inline v_exp_f32 (no libcall, no branch)
__device__ __forceinline__ float elu_fast(float a) {
    return a > 0.f ? a : (__expf(a) - 1.f);
}

#define SCORE_BLOCKS ((N_CELLS * 16 + 255) / 256)
#define ROWSTART_BLOCKS ((N_EDGES + 255) / 256)

// Dispatch 1 (fused): blocks [0,SCORE_BLOCKS) = per-cell scores + bf16 x copy
// ([N][64] rows = one 128B line each); remaining blocks = CSR row offsets.
__global__ void __launch_bounds__(256) prep_kernel(
    const float* __restrict__ x, const float* __restrict__ w,
    const int* __restrict__ tgt,
    float* __restrict__ s_src, float* __restrict__ s_tgt,
    unsigned short* __restrict__ xb, int* __restrict__ row_start,
    int n_cells, int n_edges) {
    if (blockIdx.x < SCORE_BLOCKS) {
        int gid  = blockIdx.x * 256 + threadIdx.x;
        int wave = gid >> 6;
        int lane = threadIdx.x & 63;
        int grp  = lane >> 4;
        int sub  = lane & 15;
        int cell = wave * 4 + grp;

        float4 xv = make_float4(0.f, 0.f, 0.f, 0.f);
        if (cell < n_cells)
            xv = *(const float4*)&x[(((unsigned)cell << 6) | ((unsigned)sub << 2))];
        if (xb && cell < n_cells) {
            ushort4 hb;
            hb.x = f32_to_bf16(xv.x); hb.y = f32_to_bf16(xv.y);
            hb.z = f32_to_bf16(xv.z); hb.w = f32_to_bf16(xv.w);
            *(ushort4*)&xb[(((unsigned)cell << 6) | ((unsigned)sub << 2))] = hb;
        }
        const float4* w4 = (const float4*)w;
        float4 wa = w4[sub];
        float4 wb = w4[16 + sub];
        float a = xv.x * wa.x + xv.y * wa.y + xv.z * wa.z + xv.w * wa.w;
        float b = xv.x * wb.x + xv.y * wb.y + xv.z * wb.z + xv.w * wb.w;
#pragma unroll
        for (int off = 8; off; off >>= 1) {
            a += __shfl_xor(a, off, 64);
            b += __shfl_xor(b, off, 64);
        }
        if (sub == 0 && cell < n_cells) {
            s_src[cell] = a;
            s_tgt[cell] = b;
        }
    } else {
        int e = (blockIdx.x - SCORE_BLOCKS) * 256 + threadIdx.x;
        if (e >= n_edges) return;
        int lane = threadIdx.x & 63;
        int t = tgt[e];
        int prev = __shfl_up(t, 1, 64);
        if (lane == 0) prev = (e == 0) ? -1 : tgt[e - 1];
        for (int c = prev + 1; c <= t; ++c) row_start[c] = e;
        if (e == n_edges - 1) {
            for (int c = t + 1; c <= n_cells; ++c) row_start[c] = n_edges;
        }
    }
}

// Dispatch 2: one 16-lane group per cell (grid exact). Two PARALLEL 2-deep
// load chains per window: jr -> x-gather  and  jr -> s_src -> elu (branchless);
// fma waits on whichever lands last. No vals array, no third dispatch.
__global__ void __launch_bounds__(256) agg_kernel(
    const unsigned short* __restrict__ xb, const int* __restrict__ src,
    const float* __restrict__ nbhd,
    const float* __restrict__ s_src, const float* __restrict__ s_tgt,
    const int* __restrict__ row_start,
    float* __restrict__ out, int n_cells) {
    int gid  = blockIdx.x * 256 + threadIdx.x;
    int lane = threadIdx.x & 63;
    int grp  = lane >> 4;
    int sub  = lane & 15;
    int cell = (gid >> 6) * 4 + grp;          // grid exact: always < n_cells
    unsigned suboff = (unsigned)sub << 2;
    int gbase = grp << 4;

    int lo  = row_start[cell];
    int hi  = row_start[cell + 1];
    float sti = s_tgt[cell];
    int cnt  = hi - lo;
    int cntP = cnt > (MAXW * 16) ? (MAXW * 16) : cnt;

    // Upfront: all windows' (j, nbhd) coalesced loads issue back-to-back,
    // then the dependent s_src gathers (parallel with the x-gathers below).
    int   jr[MAXW];
    float nr[MAXW];
#pragma unroll
    for (int c = 0; c < MAXW; ++c) {
        int t16 = (c << 4) + sub;
        int j = 0; float n = 0.f;
        if (t16 < cntP) {
            int idx = lo + t16;
            j = src[idx];
            n = nbhd[idx];
        }
        jr[c] = j; nr[c] = n;
    }
    float sr[MAXW];
#pragma unroll
    for (int c = 0; c < MAXW; ++c)
        sr[c] = s_src[jr[c]];                 // j=0 for inactive lanes: safe
    float vr[MAXW];
#pragma unroll
    for (int c = 0; c < MAXW; ++c)
        vr[c] = nr[c] * elu_fast(sr[c] + sti);   // branchless; x-loads hoist past

    float4 acc = make_float4(0.f, 0.f, 0.f, 0.f);
#pragma unroll
    for (int c = 0; c < MAXW; ++c) {
        int wc = cntP - (c << 4);
        if (wc <= 0) break;
        if (wc > 16) wc = 16;
        int t = 0;
        for (; t + 8 <= wc; t += 8) {
#pragma unroll
            for (int u = 0; u < 8; u += 4) {
                int   j0 = __shfl(jr[c], gbase + t + u,     64);
                int   j1 = __shfl(jr[c], gbase + t + u + 1, 64);
                int   j2 = __shfl(jr[c], gbase + t + u + 2, 64);
                int   j3 = __shfl(jr[c], gbase + t + u + 3, 64);
                float v0 = __shfl(vr[c], gbase + t + u,     64);
                float v1 = __shfl(vr[c], gbase + t + u + 1, 64);
                float v2 = __shfl(vr[c], gbase + t + u + 2, 64);
                float v3 = __shfl(vr[c], gbase + t + u + 3, 64);
                ushort4 h0 = *(const ushort4*)&xb[(((unsigned)j0 << 6) | suboff)];
                ushort4 h1 = *(const ushort4*)&xb[(((unsigned)j1 << 6) | suboff)];
                ushort4 h2 = *(const ushort4*)&xb[(((unsigned)j2 << 6) | suboff)];
                ushort4 h3 = *(const ushort4*)&xb[(((unsigned)j3 << 6) | suboff)];
                acc.x = fmaf(v0, bf16_to_f32(h0.x), acc.x);
                acc.y = fmaf(v0, bf16_to_f32(h0.y), acc.y);
                acc.z = fmaf(v0, bf16_to_f32(h0.z), acc.z);
                acc.w = fmaf(v0, bf16_to_f32(h0.w), acc.w);
                acc.x = fmaf(v1, bf16_to_f32(h1.x), acc.x);
                acc.y = fmaf(v1, bf16_to_f32(h1.y), acc.y);
                acc.z = fmaf(v1, bf16_to_f32(h1.z), acc.z);
                acc.w = fmaf(v1, bf16_to_f32(h1.w), acc.w);
                acc.x = fmaf(v2, bf16_to_f32(h2.x), acc.x);
                acc.y = fmaf(v2, bf16_to_f32(h2.y), acc.y);
                acc.z = fmaf(v2, bf16_to_f32(h2.z), acc.z);
                acc.w = fmaf(v2, bf16_to_f32(h2.w), acc.w);
                acc.x = fmaf(v3, bf16_to_f32(h3.x), acc.x);
                acc.y = fmaf(v3, bf16_to_f32(h3.y), acc.y);
                acc.z = fmaf(v3, bf16_to_f32(h3.z), acc.z);
                acc.w = fmaf(v3, bf16_to_f32(h3.w), acc.w);
            }
        }
        for (; t + 4 <= wc; t += 4) {
            int   j0 = __shfl(jr[c], gbase + t,     64);
            int   j1 = __shfl(jr[c], gbase + t + 1, 64);
            int   j2 = __shfl(jr[c], gbase + t + 2, 64);
            int   j3 = __shfl(jr[c], gbase + t + 3, 64);
            float v0 = __shfl(vr[c], gbase + t,     64);
            float v1 = __shfl(vr[c], gbase + t + 1, 64);
            float v2 = __shfl(vr[c], gbase + t + 2, 64);
            float v3 = __shfl(vr[c], gbase + t + 3, 64);
            ushort4 h0 = *(const ushort4*)&xb[(((unsigned)j0 << 6) | suboff)];
            ushort4 h1 = *(const ushort4*)&xb[(((unsigned)j1 << 6) | suboff)];
            ushort4 h2 = *(const ushort4*)&xb[(((unsigned)j2 << 6) | suboff)];
            ushort4 h3 = *(const ushort4*)&xb[(((unsigned)j3 << 6) | suboff)];
            acc.x = fmaf(v0, bf16_to_f32(h0.x), acc.x);
            acc.y = fmaf(v0, bf16_to_f32(h0.y), acc.y);
            acc.z = fmaf(v0, bf16_to_f32(h0.z), acc.z);
            acc.w = fmaf(v0, bf16_to_f32(h0.w), acc.w);
            acc.x = fmaf(v1, bf16_to_f32(h1.x), acc.x);
            acc.y = fmaf(v1, bf16_to_f32(h1.y), acc.y);
            acc.z = fmaf(v1, bf16_to_f32(h1.z), acc.z);
            acc.w = fmaf(v1, bf16_to_f32(h1.w), acc.w);
            acc.x = fmaf(v2, bf16_to_f32(h2.x), acc.x);
            acc.y = fmaf(v2, bf16_to_f32(h2.y), acc.y);
            acc.z = fmaf(v2, bf16_to_f32(h2.z), acc.z);
            acc.w = fmaf(v2, bf16_to_f32(h2.w), acc.w);
            acc.x = fmaf(v3, bf16_to_f32(h3.x), acc.x);
            acc.y = fmaf(v3, bf16_to_f32(h3.y), acc.y);
            acc.z = fmaf(v3, bf16_to_f32(h3.z), acc.z);
            acc.w = fmaf(v3, bf16_to_f32(h3.w), acc.w);
        }
        for (; t < wc; ++t) {
            int   jt = __shfl(jr[c], gbase + t, 64);
            float vt = __shfl(vr[c], gbase + t, 64);
            ushort4 h = *(const ushort4*)&xb[(((unsigned)jt << 6) | suboff)];
            acc.x = fmaf(vt, bf16_to_f32(h.x), acc.x);
            acc.y = fmaf(vt, bf16_to_f32(h.y), acc.y);
            acc.z = fmaf(vt, bf16_to_f32(h.z), acc.z);
            acc.w = fmaf(vt, bf16_to_f32(h.w), acc.w);
        }
    }

    // Tail for deg > 64 (statistically ~absent; inline v computation).
    for (int base = lo + MAXW * 16; base < hi; base += 16) {
        int cc = hi - base;
        if (cc > 16) cc = 16;
        int   j = 0;
        float v = 0.f;
        if (sub < cc) {
            j = src[base + sub];
            v = nbhd[base + sub] * elu_fast(s_src[j] + sti);
        }
        for (int t = 0; t < cc; ++t) {
            int   jt = __shfl(j, gbase + t, 64);
            float vt = __shfl(v, gbase + t, 64);
            ushort4 h = *(const ushort4*)&xb[(((unsigned)jt << 6) | suboff)];
            acc.x = fmaf(vt, bf16_to_f32(h.x), acc.x);
            acc.y = fmaf(vt, bf16_to_f32(h.y), acc.y);
            acc.z = fmaf(vt, bf16_to_f32(h.z), acc.z);
            acc.w = fmaf(vt, bf16_to_f32(h.w), acc.w);
        }
    }

    *(float4*)&out[(((unsigned)cell << 6) | suboff)] = acc;
}

// Fallback f32-gather (only if workspace too small for xb).
__global__ void __launch_bounds__(256) agg_kernel_f32(
    const float* __restrict__ x, const int* __restrict__ src,
    const float* __restrict__ nbhd,
    const float* __restrict__ s_src, const float* __restrict__ s_tgt,
    const int* __restrict__ row_start,
    float* __restrict__ out, int n_cells) {
    int gid  = blockIdx.x * 256 + threadIdx.x;
    int lane = threadIdx.x & 63;
    int grp  = lane >> 4;
    int sub  = lane & 15;
    int cell = (gid >> 6) * 4 + grp;
    unsigned suboff = (unsigned)sub << 2;
    int gbase = grp << 4;

    int lo = 0, hi = 0;
    float sti = 0.f;
    if (cell < n_cells) {
        lo  = row_start[cell];
        hi  = row_start[cell + 1];
        sti = s_tgt[cell];
    }
    float4 acc = make_float4(0.f, 0.f, 0.f, 0.f);
    for (int base = lo; base < hi; base += 16) {
        int cc = hi - base;
        if (cc > 16) cc = 16;
        int   j = 0;
        float v = 0.f;
        if (sub < cc) {
            j = src[base + sub];
            v = nbhd[base + sub] * elu_fast(s_src[j] + sti);
        }
        for (int t = 0; t < cc; ++t) {
            int   jt = __shfl(j, gbase + t, 64);
            float vt = __shfl(v, gbase + t, 64);
            float4 xt = *(const float4*)&x[(((unsigned)jt << 6) | suboff)];
            acc.x = fmaf(vt, xt.x, acc.x); acc.y = fmaf(vt, xt.y, acc.y);
            acc.z = fmaf(vt, xt.z, acc.z); acc.w = fmaf(vt, xt.w, acc.w);
        }
    }
    if (cell < n_cells)
        *(float4*)&out[(((unsigned)cell << 6) | suboff)] = acc;
}

extern "C" void kernel_launch(void* const* d_in, const int* in_sizes, int n_in,
                              void* d_out, int out_size, void* d_ws, size_t ws_size,
                              hipStream_t stream) {
    const float* x    = (const float*)d_in[0];   // [N_CELLS, 64]
    const float* w    = (const float*)d_in[1];   // [128]
    const float* nbhd = (const float*)d_in[2];   // [N_EDGES]
    const int*   tgt  = (const int*)d_in[3];     // [N_EDGES] sorted
    const int*   src  = (const int*)d_in[4];     // [N_EDGES]
    float*       out  = (float*)d_out;           // [N_CELLS, 64]

    // workspace: s_src, s_tgt, row_start, xb  (~14.0 MB)
    float* s_src     = (float*)d_ws;                              // N_CELLS
    float* s_tgt     = s_src + N_CELLS;                           // N_CELLS
    int*   row_start = (int*)(s_tgt + N_CELLS);                   // N_CELLS+1
    unsigned short* xb = (unsigned short*)(row_start + N_CELLS + 1);  // N_CELLS*64
    size_t need_full = (size_t)(3 * N_CELLS + 1) * 4 + (size_t)N_CELLS * IN_CH * 2;
    bool full = ws_size >= need_full;

    {
        int blocks = SCORE_BLOCKS + ROWSTART_BLOCKS;
        prep_kernel<<<blocks, 256, 0, stream>>>(x, w, tgt, s_src, s_tgt,
                                                full ? xb : (unsigned short*)nullptr,
                                                row_start, N_CELLS, N_EDGES);
    }
    if (full) {
        int ablocks = (N_CELLS * 16) / 256;   // exactly 6250
        agg_kernel<<<ablocks, 256, 0, stream>>>(xb, src, nbhd, s_src, s_tgt,
                                                row_start, out, N_CELLS);
    } else {
        int ablocks = (N_CELLS * 16 + 255) / 256;
        agg_kernel_f32<<<ablocks, 256, 0, stream>>>(x, src, nbhd, s_src, s_tgt,
                                                    row_start, out, N_CELLS);
    }
}

// Round 12
// 57.873 us; speedup vs baseline: 1.8897x; 1.0320x over previous
//
#include <hip/hip_runtime.h>

#define N_CELLS 100000
#define IN_CH 64
#define N_EDGES 1280000
#define MAXW 4   // 4 windows of 16 edges cached in registers (covers deg <= 64)

// ---- bf16 helpers (bit-level, RNE) ----
__device__ __forceinline__ unsigned short f32_to_bf16(float f) {
    unsigned u = __float_as_uint(f);
    u += 0x7FFFu + ((u >> 16) & 1u);
    return (unsigned short)(u >> 16);
}
__device__ __forceinline__ unsigned pack2_bf16(float lo, float hi) {
    return (unsigned)f32_to_bf16(lo) | ((unsigned)f32_to_bf16(hi) << 16);
}
__device__ __forceinline__ float bf16_to_f32(unsigned short h) {
    return __uint_as_float((unsigned)h << 16);
}
// branchless ELU: inline v_exp_f32, no libcall, no branch
__device__ __forceinline__ float elu_fast(float a) {
    return a > 0.f ? a : (__expf(a) - 1.f);
}

#define SCORE_BLOCKS 3125     // 3125 blocks * 4 waves * 8 cells = 100000 exactly
#define ROWSTART_BLOCKS 1250  // 1250 blocks * 256 thr * 4 edges = 1280000 exactly

// Dispatch 1 (fused): blocks [0,3125) = scores + bf16 x copy (8 lanes/cell,
// 16B packed stores); blocks [3125,4375) = CSR row offsets (int4 tgt loads).
__global__ void __launch_bounds__(256) prep_kernel(
    const float* __restrict__ x, const float* __restrict__ w,
    const int* __restrict__ tgt,
    float* __restrict__ s_src, float* __restrict__ s_tgt,
    unsigned short* __restrict__ xb, int* __restrict__ row_start,
    int n_cells, int n_edges) {
    if (blockIdx.x < SCORE_BLOCKS) {
        int gid  = blockIdx.x * 256 + threadIdx.x;
        int wave = gid >> 6;
        int lane = threadIdx.x & 63;
        int grp  = lane >> 3;        // 8 cells per wave
        int sl   = lane & 7;         // 8 lanes per cell, 8 channels each
        int cell = wave * 8 + grp;   // always < n_cells (grid exact)

        unsigned base = ((unsigned)cell << 6) | ((unsigned)sl << 3);
        float4 xa = *(const float4*)&x[base];
        float4 xc = *(const float4*)&x[base + 4];
        if (xb) {
            uint4 p;
            p.x = pack2_bf16(xa.x, xa.y);
            p.y = pack2_bf16(xa.z, xa.w);
            p.z = pack2_bf16(xc.x, xc.y);
            p.w = pack2_bf16(xc.z, xc.w);
            *(uint4*)&xb[base] = p;   // 16B store, 16B aligned
        }
        const float4* w4 = (const float4*)w;
        float4 wa0 = w4[2 * sl],      wa1 = w4[2 * sl + 1];
        float4 wb0 = w4[16 + 2 * sl], wb1 = w4[16 + 2 * sl + 1];
        float a = xa.x * wa0.x + xa.y * wa0.y + xa.z * wa0.z + xa.w * wa0.w
                + xc.x * wa1.x + xc.y * wa1.y + xc.z * wa1.z + xc.w * wa1.w;
        float b = xa.x * wb0.x + xa.y * wb0.y + xa.z * wb0.z + xa.w * wb0.w
                + xc.x * wb1.x + xc.y * wb1.y + xc.z * wb1.z + xc.w * wb1.w;
#pragma unroll
        for (int off = 4; off; off >>= 1) {
            a += __shfl_xor(a, off, 64);
            b += __shfl_xor(b, off, 64);
        }
        if (sl == 0) {
            s_src[cell] = a;
            s_tgt[cell] = b;
        }
    } else {
        int tid4 = (blockIdx.x - SCORE_BLOCKS) * 256 + threadIdx.x;
        int e4   = tid4 * 4;          // grid exact: e4+3 <= n_edges-1
        int lane = threadIdx.x & 63;
        int4 t4 = *(const int4*)&tgt[e4];
        int prev0 = __shfl_up(t4.w, 1, 64);
        if (lane == 0) prev0 = (e4 == 0) ? -1 : tgt[e4 - 1];
        for (int c = prev0 + 1;  c <= t4.x; ++c) row_start[c] = e4;
        for (int c = t4.x + 1;   c <= t4.y; ++c) row_start[c] = e4 + 1;
        for (int c = t4.y + 1;   c <= t4.z; ++c) row_start[c] = e4 + 2;
        for (int c = t4.z + 1;   c <= t4.w; ++c) row_start[c] = e4 + 3;
        if (e4 + 3 == n_edges - 1) {
            for (int c = t4.w + 1; c <= n_cells; ++c) row_start[c] = n_edges;
        }
    }
}

// Dispatch 2: one 16-lane group per cell (grid exact). Two PARALLEL 2-deep
// load chains per window: jr -> x-gather  and  jr -> s_src -> elu (branchless).
__global__ void __launch_bounds__(256) agg_kernel(
    const unsigned short* __restrict__ xb, const int* __restrict__ src,
    const float* __restrict__ nbhd,
    const float* __restrict__ s_src, const float* __restrict__ s_tgt,
    const int* __restrict__ row_start,
    float* __restrict__ out, int n_cells) {
    int gid  = blockIdx.x * 256 + threadIdx.x;
    int lane = threadIdx.x & 63;
    int grp  = lane >> 4;
    int sub  = lane & 15;
    int cell = (gid >> 6) * 4 + grp;          // grid exact: always < n_cells
    unsigned suboff = (unsigned)sub << 2;
    int gbase = grp << 4;

    int lo  = row_start[cell];
    int hi  = row_start[cell + 1];
    float sti = s_tgt[cell];
    int cnt  = hi - lo;
    int cntP = cnt > (MAXW * 16) ? (MAXW * 16) : cnt;

    int   jr[MAXW];
    float nr[MAXW];
#pragma unroll
    for (int c = 0; c < MAXW; ++c) {
        int t16 = (c << 4) + sub;
        int j = 0; float n = 0.f;
        if (t16 < cntP) {
            int idx = lo + t16;
            j = src[idx];
            n = nbhd[idx];
        }
        jr[c] = j; nr[c] = n;
    }
    float sr[MAXW];
#pragma unroll
    for (int c = 0; c < MAXW; ++c)
        sr[c] = s_src[jr[c]];
    float vr[MAXW];
#pragma unroll
    for (int c = 0; c < MAXW; ++c)
        vr[c] = nr[c] * elu_fast(sr[c] + sti);

    float4 acc = make_float4(0.f, 0.f, 0.f, 0.f);
#pragma unroll
    for (int c = 0; c < MAXW; ++c) {
        int wc = cntP - (c << 4);
        if (wc <= 0) break;
        if (wc > 16) wc = 16;
        int t = 0;
        for (; t + 8 <= wc; t += 8) {
#pragma unroll
            for (int u = 0; u < 8; u += 4) {
                int   j0 = __shfl(jr[c], gbase + t + u,     64);
                int   j1 = __shfl(jr[c], gbase + t + u + 1, 64);
                int   j2 = __shfl(jr[c], gbase + t + u + 2, 64);
                int   j3 = __shfl(jr[c], gbase + t + u + 3, 64);
                float v0 = __shfl(vr[c], gbase + t + u,     64);
                float v1 = __shfl(vr[c], gbase + t + u + 1, 64);
                float v2 = __shfl(vr[c], gbase + t + u + 2, 64);
                float v3 = __shfl(vr[c], gbase + t + u + 3, 64);
                ushort4 h0 = *(const ushort4*)&xb[(((unsigned)j0 << 6) | suboff)];
                ushort4 h1 = *(const ushort4*)&xb[(((unsigned)j1 << 6) | suboff)];
                ushort4 h2 = *(const ushort4*)&xb[(((unsigned)j2 << 6) | suboff)];
                ushort4 h3 = *(const ushort4*)&xb[(((unsigned)j3 << 6) | suboff)];
                acc.x = fmaf(v0, bf16_to_f32(h0.x), acc.x);
                acc.y = fmaf(v0, bf16_to_f32(h0.y), acc.y);
                acc.z = fmaf(v0, bf16_to_f32(h0.z), acc.z);
                acc.w = fmaf(v0, bf16_to_f32(h0.w), acc.w);
                acc.x = fmaf(v1, bf16_to_f32(h1.x), acc.x);
                acc.y = fmaf(v1, bf16_to_f32(h1.y), acc.y);
                acc.z = fmaf(v1, bf16_to_f32(h1.z), acc.z);
                acc.w = fmaf(v1, bf16_to_f32(h1.w), acc.w);
                acc.x = fmaf(v2, bf16_to_f32(h2.x), acc.x);
                acc.y = fmaf(v2, bf16_to_f32(h2.y), acc.y);
                acc.z = fmaf(v2, bf16_to_f32(h2.z), acc.z);
                acc.w = fmaf(v2, bf16_to_f32(h2.w), acc.w);
                acc.x = fmaf(v3, bf16_to_f32(h3.x), acc.x);
                acc.y = fmaf(v3, bf16_to_f32(h3.y), acc.y);
                acc.z = fmaf(v3, bf16_to_f32(h3.z), acc.z);
                acc.w = fmaf(v3, bf16_to_f32(h3.w), acc.w);
            }
        }
        for (; t + 4 <= wc; t += 4) {
            int   j0 = __shfl(jr[c], gbase + t,     64);
            int   j1 = __shfl(jr[c], gbase + t + 1, 64);
            int   j2 = __shfl(jr[c], gbase + t + 2, 64);
            int   j3 = __shfl(jr[c], gbase + t + 3, 64);
            float v0 = __shfl(vr[c], gbase + t,     64);
            float v1 = __shfl(vr[c], gbase + t + 1, 64);
            float v2 = __shfl(vr[c], gbase + t + 2, 64);
            float v3 = __shfl(vr[c], gbase + t + 3, 64);
            ushort4 h0 = *(const ushort4*)&xb[(((unsigned)j0 << 6) | suboff)];
            ushort4 h1 = *(const ushort4*)&xb[(((unsigned)j1 << 6) | suboff)];
            ushort4 h2 = *(const ushort4*)&xb[(((unsigned)j2 << 6) | suboff)];
            ushort4 h3 = *(const ushort4*)&xb[(((unsigned)j3 << 6) | suboff)];
            acc.x = fmaf(v0, bf16_to_f32(h0.x), acc.x);
            acc.y = fmaf(v0, bf16_to_f32(h0.y), acc.y);
            acc.z = fmaf(v0, bf16_to_f32(h0.z), acc.z);
            acc.w = fmaf(v0, bf16_to_f32(h0.w), acc.w);
            acc.x = fmaf(v1, bf16_to_f32(h1.x), acc.x);
            acc.y = fmaf(v1, bf16_to_f32(h1.y), acc.y);
            acc.z = fmaf(v1, bf16_to_f32(h1.z), acc.z);
            acc.w = fmaf(v1, bf16_to_f32(h1.w), acc.w);
            acc.x = fmaf(v2, bf16_to_f32(h2.x), acc.x);
            acc.y = fmaf(v2, bf16_to_f32(h2.y), acc.y);
            acc.z = fmaf(v2, bf16_to_f32(h2.z), acc.z);
            acc.w = fmaf(v2, bf16_to_f32(h2.w), acc.w);
            acc.x = fmaf(v3, bf16_to_f32(h3.x), acc.x);
            acc.y = fmaf(v3, bf16_to_f32(h3.y), acc.y);
            acc.z = fmaf(v3, bf16_to_f32(h3.z), acc.z);
            acc.w = fmaf(v3, bf16_to_f32(h3.w), acc.w);
        }
        for (; t < wc; ++t) {
            int   jt = __shfl(jr[c], gbase + t, 64);
            float vt = __shfl(vr[c], gbase + t, 64);
            ushort4 h = *(const ushort4*)&xb[(((unsigned)jt << 6) | suboff)];
            acc.x = fmaf(vt, bf16_to_f32(h.x), acc.x);
            acc.y = fmaf(vt, bf16_to_f32(h.y), acc.y);
            acc.z = fmaf(vt, bf16_to_f32(h.z), acc.z);
            acc.w = fmaf(vt, bf16_to_f32(h.w), acc.w);
        }
    }

    // Tail for deg > 64 (statistically ~absent).
    for (int base = lo + MAXW * 16; base < hi; base += 16) {
        int cc = hi - base;
        if (cc > 16) cc = 16;
        int   j = 0;
        float v = 0.f;
        if (sub < cc) {
            j = src[base + sub];
            v = nbhd[base + sub] * elu_fast(s_src[j] + sti);
        }
        for (int t = 0; t < cc; ++t) {
            int   jt = __shfl(j, gbase + t, 64);
            float vt = __shfl(v, gbase + t, 64);
            ushort4 h = *(const ushort4*)&xb[(((unsigned)jt << 6) | suboff)];
            acc.x = fmaf(vt, bf16_to_f32(h.x), acc.x);
            acc.y = fmaf(vt, bf16_to_f32(h.y), acc.y);
            acc.z = fmaf(vt, bf16_to_f32(h.z), acc.z);
            acc.w = fmaf(vt, bf16_to_f32(h.w), acc.w);
        }
    }

    *(float4*)&out[(((unsigned)cell << 6) | suboff)] = acc;
}

// Fallback f32-gather (only if workspace too small for xb).
__global__ void __launch_bounds__(256) agg_kernel_f32(
    const float* __restrict__ x, const int* __restrict__ src,
    const float* __restrict__ nbhd,
    const float* __restrict__ s_src, const float* __restrict__ s_tgt,
    const int* __restrict__ row_start,
    float* __restrict__ out, int n_cells) {
    int gid  = blockIdx.x * 256 + threadIdx.x;
    int lane = threadIdx.x & 63;
    int grp  = lane >> 4;
    int sub  = lane & 15;
    int cell = (gid >> 6) * 4 + grp;
    unsigned suboff = (unsigned)sub << 2;
    int gbase = grp << 4;

    int lo = 0, hi = 0;
    float sti = 0.f;
    if (cell < n_cells) {
        lo  = row_start[cell];
        hi  = row_start[cell + 1];
        sti = s_tgt[cell];
    }
    float4 acc = make_float4(0.f, 0.f, 0.f, 0.f);
    for (int base = lo; base < hi; base += 16) {
        int cc = hi - base;
        if (cc > 16) cc = 16;
        int   j = 0;
        float v = 0.f;
        if (sub < cc) {
            j = src[base + sub];
            v = nbhd[base + sub] * elu_fast(s_src[j] + sti);
        }
        for (int t = 0; t < cc; ++t) {
            int   jt = __shfl(j, gbase + t, 64);
            float vt = __shfl(v, gbase + t, 64);
            float4 xt = *(const float4*)&x[(((unsigned)jt << 6) | suboff)];
            acc.x = fmaf(vt, xt.x, acc.x); acc.y = fmaf(vt, xt.y, acc.y);
            acc.z = fmaf(vt, xt.z, acc.z); acc.w = fmaf(vt, xt.w, acc.w);
        }
    }
    if (cell < n_cells)
        *(float4*)&out[(((unsigned)cell << 6) | suboff)] = acc;
}

extern "C" void kernel_launch(void* const* d_in, const int* in_sizes, int n_in,
                              void* d_out, int out_size, void* d_ws, size_t ws_size,
                              hipStream_t stream) {
    const float* x    = (const float*)d_in[0];   // [N_CELLS, 64]
    const float* w    = (const float*)d_in[1];   // [128]
    const float* nbhd = (const float*)d_in[2];   // [N_EDGES]
    const int*   tgt  = (const int*)d_in[3];     // [N_EDGES] sorted
    const int*   src  = (const int*)d_in[4];     // [N_EDGES]
    float*       out  = (float*)d_out;           // [N_CELLS, 64]

    // workspace: s_src, s_tgt, row_start, xb  (~14.0 MB)
    float* s_src     = (float*)d_ws;                              // N_CELLS
    float* s_tgt     = s_src + N_CELLS;                           // N_CELLS
    int*   row_start = (int*)(s_tgt + N_CELLS);                   // N_CELLS+1
    unsigned short* xb = (unsigned short*)(row_start + N_CELLS + 1);  // N_CELLS*64
    size_t need_full = (size_t)(3 * N_CELLS + 1) * 4 + (size_t)N_CELLS * IN_CH * 2;
    bool full = ws_size >= need_full;

    {
        int blocks = SCORE_BLOCKS + ROWSTART_BLOCKS;   // 4375
        prep_kernel<<<blocks, 256, 0, stream>>>(x, w, tgt, s_src, s_tgt,
                                                full ? xb : (unsigned short*)nullptr,
                                                row_start, N_CELLS, N_EDGES);
    }
    if (full) {
        int ablocks = (N_CELLS * 16) / 256;   // exactly 6250
        agg_kernel<<<ablocks, 256, 0, stream>>>(xb, src, nbhd, s_src, s_tgt,
                                                row_start, out, N_CELLS);
    } else {
        int ablocks = (N_CELLS * 16 + 255) / 256;
        agg_kernel_f32<<<ablocks, 256, 0, stream>>>(x, src, nbhd, s_src, s_tgt,
                                                    row_start, out, N_CELLS);
    }
}